// Round 1
// baseline (239.928 us; speedup 1.0000x reference)
//
#include <hip/hip_runtime.h>
#include <stdint.h>
#include <stddef.h>

typedef __bf16 bf16;
typedef __bf16 bf16x8 __attribute__((ext_vector_type(8)));
typedef float f32x4 __attribute__((ext_vector_type(4)));

// ---------------------------------------------------------------------------
// async global->LDS, 16B per lane. LDS dest is wave-uniform base + lane*16.
// CK-style addrspace casts (reinterpret via uintptr_t).
// ---------------------------------------------------------------------------
__device__ __forceinline__ void global_to_lds16(const void* g, void* l) {
  const __attribute__((address_space(1))) unsigned* gp =
      reinterpret_cast<const __attribute__((address_space(1))) unsigned*>(
          reinterpret_cast<uintptr_t>(g));
  __attribute__((address_space(3))) unsigned* lp =
      reinterpret_cast<__attribute__((address_space(3))) unsigned*>(
          reinterpret_cast<uintptr_t>(l));
  __builtin_amdgcn_global_load_lds(gp, lp, 16, 0, 0);
}

// ---------------------------------------------------------------------------
// fp32 -> bf16 converter, 8 elems/thread. n must be multiple of 2048*gridDim.
// ---------------------------------------------------------------------------
__global__ __launch_bounds__(256) void cvt_f32_bf16(const float* __restrict__ src,
                                                    bf16* __restrict__ dst) {
  int i = (blockIdx.x * 256 + threadIdx.x) * 8;
  float4 a = *(const float4*)(src + i);
  float4 b = *(const float4*)(src + i + 4);
  bf16x8 o;
  o[0] = (bf16)a.x; o[1] = (bf16)a.y; o[2] = (bf16)a.z; o[3] = (bf16)a.w;
  o[4] = (bf16)b.x; o[5] = (bf16)b.y; o[6] = (bf16)b.z; o[7] = (bf16)b.w;
  *(bf16x8*)(dst + i) = o;
}

struct CvtBatch { const float* src[5]; bf16* dst[5]; };
__global__ __launch_bounds__(256) void cvt_f32_bf16_batch(CvtBatch cb) {
  const float* src = cb.src[blockIdx.z];
  bf16* dst = cb.dst[blockIdx.z];
  int i = (blockIdx.x * 256 + threadIdx.x) * 8;
  float4 a = *(const float4*)(src + i);
  float4 b = *(const float4*)(src + i + 4);
  bf16x8 o;
  o[0] = (bf16)a.x; o[1] = (bf16)a.y; o[2] = (bf16)a.z; o[3] = (bf16)a.w;
  o[4] = (bf16)b.x; o[5] = (bf16)b.y; o[6] = (bf16)b.z; o[7] = (bf16)b.w;
  *(bf16x8*)(dst + i) = o;
}

// ---------------------------------------------------------------------------
// fp32 1024x1024 -> bf16 transposed. 64x64 LDS tile, pad +1 elem.
// ---------------------------------------------------------------------------
struct TrBatch { const float* src[6]; bf16* dst[6]; };
__global__ __launch_bounds__(256) void transpose_cvt_batch(TrBatch tb) {
  const float* __restrict__ src = tb.src[blockIdx.z];
  bf16* __restrict__ dst = tb.dst[blockIdx.z];
  __shared__ bf16 tile[64][65];
  const int bx = blockIdx.x * 64;  // src col base
  const int by = blockIdx.y * 64;  // src row base
  const int tx = threadIdx.x & 63;
  const int ty4 = threadIdx.x >> 6;  // 0..3
#pragma unroll
  for (int rr = 0; rr < 16; rr++) {
    int row = ty4 * 16 + rr;
    tile[row][tx] = (bf16)src[(size_t)(by + row) * 1024 + bx + tx];
  }
  __syncthreads();
#pragma unroll
  for (int rr = 0; rr < 16; rr++) {
    int row = ty4 * 16 + rr;
    dst[(size_t)(bx + row) * 1024 + by + tx] = tile[tx][row];
  }
}

// ---------------------------------------------------------------------------
// perm normalization: handles both int32[256] and int64[256] device layouts.
// Only reads first 1024 bytes for detection (safe for both).
// ---------------------------------------------------------------------------
__global__ __launch_bounds__(256) void normalize_perm(const int* __restrict__ raw,
                                                      int* __restrict__ pout) {
  __shared__ int nz;
  if (threadIdx.x == 0) nz = 0;
  __syncthreads();
  if (threadIdx.x < 128) {
    if (raw[2 * threadIdx.x + 1] != 0) atomicAdd(&nz, 1);
  }
  __syncthreads();
  int k = threadIdx.x;
  pout[k] = (nz == 0) ? raw[2 * k] : raw[k];
}

__global__ __launch_bounds__(256) void zero_f32(float* __restrict__ p) {
  int i = (blockIdx.x * 256 + threadIdx.x) * 4;
  *(float4*)(p + i) = make_float4(0.f, 0.f, 0.f, 0.f);
}

// G[j,d] = sum_{k: perm[k]==d} W_dec[j,k].  grid = 1024 blocks x 256 thr.
__global__ __launch_bounds__(256) void scatter_g(const float* __restrict__ Wdec,
                                                 const int* __restrict__ perm,
                                                 float* __restrict__ G) {
  int idx = blockIdx.x * 256 + threadIdx.x;
  int j = idx >> 8, k = idx & 255;
  atomicAdd(G + (size_t)j * 1024 + perm[k], Wdec[(size_t)j * 256 + k]);
}

// ---------------------------------------------------------------------------
// 64x64-tile NT GEMM, all matrices 1024x1024 bf16, C = A * B^T (bf16 out).
// 256 thr = 4 waves in 2x2; each wave 32x32 (2x2 MFMA 16x16x32 frags).
// Batched via blockIdx.z with pointer tables.
// ---------------------------------------------------------------------------
struct GemmBatch { const bf16* A[6]; const bf16* B[6]; bf16* C[6]; };

__global__ __launch_bounds__(256) void gemm64_nt(GemmBatch bt) {
  const bf16* __restrict__ A = bt.A[blockIdx.z];
  const bf16* __restrict__ B = bt.B[blockIdx.z];
  bf16* __restrict__ C = bt.C[blockIdx.z];

  __shared__ bf16 As[64 * 32];
  __shared__ bf16 Bs[64 * 32];

  const int tid = threadIdx.x;
  const int wave = tid >> 6, lane = tid & 63;
  const int quad = lane >> 4, l16 = lane & 15;
  const int rowBase = blockIdx.y * 64;
  const int colBase = blockIdx.x * 64;
  const int waveM = (wave >> 1) * 32, waveN = (wave & 1) * 32;

  const int e = tid * 8;
  const int sr = e >> 5, sc = e & 31;
  const bf16* Ag = A + (size_t)(rowBase + sr) * 1024 + sc;
  const bf16* Bg = B + (size_t)(colBase + sr) * 1024 + sc;
  char* AsB = (char*)As + wave * 1024;
  char* BsB = (char*)Bs + wave * 1024;

  f32x4 acc[2][2] = {};

  for (int k0 = 0; k0 < 1024; k0 += 32) {
    global_to_lds16(Ag + k0, AsB);
    global_to_lds16(Bg + k0, BsB);
    __syncthreads();
    bf16x8 af[2], bfr[2];
#pragma unroll
    for (int mi = 0; mi < 2; mi++)
      af[mi] = *(const bf16x8*)(As + (waveM + mi * 16 + l16) * 32 + quad * 8);
#pragma unroll
    for (int ni = 0; ni < 2; ni++)
      bfr[ni] = *(const bf16x8*)(Bs + (waveN + ni * 16 + l16) * 32 + quad * 8);
#pragma unroll
    for (int mi = 0; mi < 2; mi++)
#pragma unroll
      for (int ni = 0; ni < 2; ni++)
        acc[mi][ni] = __builtin_amdgcn_mfma_f32_16x16x32_bf16(af[mi], bfr[ni],
                                                              acc[mi][ni], 0, 0, 0);
    __syncthreads();
  }

  bf16* Cb = C + (size_t)(rowBase + waveM) * 1024 + colBase + waveN;
#pragma unroll
  for (int mi = 0; mi < 2; mi++)
#pragma unroll
    for (int ni = 0; ni < 2; ni++)
#pragma unroll
      for (int r = 0; r < 4; r++)
        Cb[(size_t)(mi * 16 + quad * 4 + r) * 1024 + ni * 16 + l16] =
            (bf16)acc[mi][ni][r];
}

// ---------------------------------------------------------------------------
// 128x128-tile NT GEMM (m97 structure): out = x * F^T, fp32 out.
// M=8192, N=1024, K=1024, lda=ldb=ldc=1024.
// ---------------------------------------------------------------------------
__global__ __launch_bounds__(256) void gemm128_nt_f32(const bf16* __restrict__ A,
                                                      const bf16* __restrict__ B,
                                                      float* __restrict__ C) {
  __shared__ bf16 As[128 * 32];
  __shared__ bf16 Bs[128 * 32];

  const int tid = threadIdx.x;
  const int wave = tid >> 6, lane = tid & 63;
  const int quad = lane >> 4, l16 = lane & 15;
  const int rowBase = blockIdx.y * 128;
  const int colBase = blockIdx.x * 128;
  const int waveM = (wave >> 1) * 64, waveN = (wave & 1) * 64;

  const int e = tid * 8;
  const int sr = e >> 5, sc = e & 31;
  const bf16* Ag0 = A + (size_t)(rowBase + sr) * 1024 + sc;
  const bf16* Ag1 = Ag0 + (size_t)64 * 1024;
  const bf16* Bg0 = B + (size_t)(colBase + sr) * 1024 + sc;
  const bf16* Bg1 = Bg0 + (size_t)64 * 1024;
  char* AsB0 = (char*)As + wave * 1024;
  char* AsB1 = AsB0 + 4096;
  char* BsB0 = (char*)Bs + wave * 1024;
  char* BsB1 = BsB0 + 4096;

  f32x4 acc[4][4] = {};

  for (int k0 = 0; k0 < 1024; k0 += 32) {
    global_to_lds16(Ag0 + k0, AsB0);
    global_to_lds16(Ag1 + k0, AsB1);
    global_to_lds16(Bg0 + k0, BsB0);
    global_to_lds16(Bg1 + k0, BsB1);
    __syncthreads();
    bf16x8 af[4], bfr[4];
#pragma unroll
    for (int mi = 0; mi < 4; mi++)
      af[mi] = *(const bf16x8*)(As + (waveM + mi * 16 + l16) * 32 + quad * 8);
#pragma unroll
    for (int ni = 0; ni < 4; ni++)
      bfr[ni] = *(const bf16x8*)(Bs + (waveN + ni * 16 + l16) * 32 + quad * 8);
#pragma unroll
    for (int mi = 0; mi < 4; mi++)
#pragma unroll
      for (int ni = 0; ni < 4; ni++)
        acc[mi][ni] = __builtin_amdgcn_mfma_f32_16x16x32_bf16(af[mi], bfr[ni],
                                                              acc[mi][ni], 0, 0, 0);
    __syncthreads();
  }

  float* Cb = C + (size_t)(rowBase + waveM) * 1024 + colBase + waveN;
#pragma unroll
  for (int mi = 0; mi < 4; mi++)
#pragma unroll
    for (int ni = 0; ni < 4; ni++)
#pragma unroll
      for (int r = 0; r < 4; r++)
        Cb[(size_t)(mi * 16 + quad * 4 + r) * 1024 + ni * 16 + l16] =
            acc[mi][ni][r];
}

// ---------------------------------------------------------------------------
// Host launcher.
// out = x @ (G * W9 * W8 * W8 * W7 * W6 * W5 * W4 * W3 * W2 * W1 * W0)^T
// Tree: P0=G*W9  P1=W8*W8  P2=W7*W6  P3=W5*W4  P4=W3*W2  P5=W1*W0
//       Q0=P0*P1 Q1=P2*P3  Q2=P4*P5 ; R=Q0*Q1 ; F=R*Q2 ; out=NT(x,F)
// NT(A,B)=A*B^T; transposed nodes via (A*B)^T = NT(B^T, A).
// ---------------------------------------------------------------------------
extern "C" void kernel_launch(void* const* d_in, const int* in_sizes, int n_in,
                              void* d_out, int out_size, void* d_ws, size_t ws_size,
                              hipStream_t stream) {
  const float* x    = (const float*)d_in[0];
  const float* Wsrc = (const float*)d_in[1];   // 10 x 1024 x 1024
  const float* Wdec = (const float*)d_in[2];   // 1024 x 256
  const int*   praw = (const int*)d_in[3];
  float* out = (float*)d_out;

  constexpr size_t MAT  = 1024ull * 1024ull;   // elements per DxD matrix
  constexpr size_t SLOT = 2ull * 1024 * 1024;  // 2 MiB (one bf16 DxD matrix)

  char* ws = (char*)d_ws;
  bf16* Wrm[5];  // W1, W3, W5, W7, W8 (row-major bf16)
  for (int i = 0; i < 5; i++) Wrm[i] = (bf16*)(ws + (size_t)i * SLOT);
  bf16* Wt[6];   // W0^T, W2^T, W4^T, W6^T, W8^T, W9^T
  for (int i = 0; i < 6; i++) Wt[i] = (bf16*)(ws + (size_t)(5 + i) * SLOT);
  bf16* Gbf = (bf16*)(ws + 11 * SLOT);
  bf16* xbf = (bf16*)(ws + 12 * SLOT);         // 8 slots (16 MiB)
  bf16* P[6];
  for (int i = 0; i < 6; i++) P[i] = (bf16*)(ws + (size_t)(20 + i) * SLOT);
  bf16* Q[3];
  for (int i = 0; i < 3; i++) Q[i] = (bf16*)(ws + (size_t)(26 + i) * SLOT);
  bf16* Rb = (bf16*)(ws + 29 * SLOT);
  bf16* Fb = (bf16*)(ws + 30 * SLOT);
  float* Gf32 = (float*)(ws + 20 * SLOT);      // alias P0/P1t (dead before L1)
  int* permN = (int*)(ws + 31 * SLOT);         // total ws use: 62 MiB + 1 KiB

  // 1) leaf conversions
  CvtBatch cb;
  const int rmIdx[5] = {1, 3, 5, 7, 8};
  for (int i = 0; i < 5; i++) { cb.src[i] = Wsrc + (size_t)rmIdx[i] * MAT; cb.dst[i] = Wrm[i]; }
  cvt_f32_bf16_batch<<<dim3(512, 1, 5), 256, 0, stream>>>(cb);

  TrBatch tb;
  const int trIdx[6] = {0, 2, 4, 6, 8, 9};
  for (int i = 0; i < 6; i++) { tb.src[i] = Wsrc + (size_t)trIdx[i] * MAT; tb.dst[i] = Wt[i]; }
  transpose_cvt_batch<<<dim3(16, 16, 6), 256, 0, stream>>>(tb);

  cvt_f32_bf16<<<4096, 256, 0, stream>>>(x, xbf);  // 8192x1024

  // 2) build G from perm + W_dec
  zero_f32<<<1024, 256, 0, stream>>>(Gf32);
  normalize_perm<<<1, 256, 0, stream>>>(praw, permN);
  scatter_g<<<1024, 256, 0, stream>>>(Wdec, permN, Gf32);
  cvt_f32_bf16<<<512, 256, 0, stream>>>(Gf32, Gbf);

  // 3) tree level 1 (6 GEMMs, batched)
  GemmBatch L1;
  const bf16* l1a[6] = {Gbf, Wt[4], Wrm[3], Wt[2], Wrm[1], Wt[0]};
  const bf16* l1b[6] = {Wt[5], Wrm[4], Wt[3], Wrm[2], Wt[1], Wrm[0]};
  for (int i = 0; i < 6; i++) { L1.A[i] = l1a[i]; L1.B[i] = l1b[i]; L1.C[i] = P[i]; }
  gemm64_nt<<<dim3(16, 16, 6), 256, 0, stream>>>(L1);

  // 4) tree level 2 (3 GEMMs): Q0=NT(P0,P1t) Q1t=NT(P3t,P2) Q2t=NT(P5t,P4)
  GemmBatch L2;
  const bf16* l2a[3] = {P[0], P[3], P[5]};
  const bf16* l2b[3] = {P[1], P[2], P[4]};
  for (int i = 0; i < 3; i++) { L2.A[i] = l2a[i]; L2.B[i] = l2b[i]; L2.C[i] = Q[i]; }
  gemm64_nt<<<dim3(16, 16, 3), 256, 0, stream>>>(L2);

  // 5) level 3: R = NT(Q0, Q1t)
  GemmBatch L3{};
  L3.A[0] = Q[0]; L3.B[0] = Q[1]; L3.C[0] = Rb;
  gemm64_nt<<<dim3(16, 16, 1), 256, 0, stream>>>(L3);

  // 6) level 4: F = NT(R, Q2t)
  GemmBatch L4{};
  L4.A[0] = Rb; L4.B[0] = Q[2]; L4.C[0] = Fb;
  gemm64_nt<<<dim3(16, 16, 1), 256, 0, stream>>>(L4);

  // 7) out = NT(x, F), fp32 out
  gemm128_nt_f32<<<dim3(8, 64), 256, 0, stream>>>(xbf, Fb, out);

  (void)in_sizes; (void)n_in; (void)out_size; (void)ws_size;
}

// Round 2
// 222.453 us; speedup vs baseline: 1.0786x; 1.0786x over previous
//
#include <hip/hip_runtime.h>
#include <stdint.h>
#include <stddef.h>

typedef __bf16 bf16;
typedef __bf16 bf16x8 __attribute__((ext_vector_type(8)));
typedef float f32x4 __attribute__((ext_vector_type(4)));

// ---------------------------------------------------------------------------
// async global->LDS, 16B per lane. LDS dest is wave-uniform base + lane*16.
// ---------------------------------------------------------------------------
__device__ __forceinline__ void global_to_lds16(const void* g, void* l) {
  const __attribute__((address_space(1))) unsigned* gp =
      reinterpret_cast<const __attribute__((address_space(1))) unsigned*>(
          reinterpret_cast<uintptr_t>(g));
  __attribute__((address_space(3))) unsigned* lp =
      reinterpret_cast<__attribute__((address_space(3))) unsigned*>(
          reinterpret_cast<uintptr_t>(l));
  __builtin_amdgcn_global_load_lds(gp, lp, 16, 0, 0);
}

// ---------------------------------------------------------------------------
// ONE fused prep kernel. Flat grid of 9216 independent blocks:
//   [0,    2560)  : fp32->bf16 convert of 5 row-major Ws (512 blocks each)
//   [2560, 4096)  : fp32->bf16 transpose of 6 Ws (256 blocks each)
//   [4096, 8192)  : fp32->bf16 convert of x (8192x1024)
//   [8192, 9216)  : G build, one block per row j: LDS-local scatter of
//                   W_dec row via perm (inline int32/int64 decode), bf16 out
// ---------------------------------------------------------------------------
struct PrepArgs {
  const float* cvt_src[5]; bf16* cvt_dst[5];
  const float* tr_src[6];  bf16* tr_dst[6];
  const float* x; bf16* xbf;
  const float* Wdec; const int* praw; bf16* Gbf;
};

__global__ __launch_bounds__(256) void prep_all(PrepArgs p) {
  __shared__ alignas(16) char smem[64 * 65 * 2];  // 8320 B, max of all branches
  const int b = blockIdx.x;
  const int tid = threadIdx.x;

  if (b < 2560) {  // ---- convert row-major W ----
    const int m = b >> 9, blk = b & 511;
    const float* __restrict__ src = p.cvt_src[m];
    bf16* __restrict__ dst = p.cvt_dst[m];
    const int i = (blk * 256 + tid) * 8;
    float4 a = *(const float4*)(src + i);
    float4 c = *(const float4*)(src + i + 4);
    bf16x8 o;
    o[0] = (bf16)a.x; o[1] = (bf16)a.y; o[2] = (bf16)a.z; o[3] = (bf16)a.w;
    o[4] = (bf16)c.x; o[5] = (bf16)c.y; o[6] = (bf16)c.z; o[7] = (bf16)c.w;
    *(bf16x8*)(dst + i) = o;
  } else if (b < 4096) {  // ---- transpose+convert W ----
    const int t = b - 2560;
    const int m = t >> 8, r = t & 255;
    const float* __restrict__ src = p.tr_src[m];
    bf16* __restrict__ dst = p.tr_dst[m];
    bf16(*tile)[65] = reinterpret_cast<bf16(*)[65]>(smem);
    const int bx = (r & 15) * 64;  // src col base
    const int by = (r >> 4) * 64;  // src row base
    const int tx = tid & 63;
    const int ty4 = tid >> 6;  // 0..3
#pragma unroll
    for (int rr = 0; rr < 16; rr++) {
      int row = ty4 * 16 + rr;
      tile[row][tx] = (bf16)src[(size_t)(by + row) * 1024 + bx + tx];
    }
    __syncthreads();
#pragma unroll
    for (int rr = 0; rr < 16; rr++) {
      int row = ty4 * 16 + rr;
      dst[(size_t)(bx + row) * 1024 + by + tx] = tile[tx][row];
    }
  } else if (b < 8192) {  // ---- convert x ----
    const int blk = b - 4096;
    const int i = (blk * 256 + tid) * 8;
    float4 a = *(const float4*)(p.x + i);
    float4 c = *(const float4*)(p.x + i + 4);
    bf16x8 o;
    o[0] = (bf16)a.x; o[1] = (bf16)a.y; o[2] = (bf16)a.z; o[3] = (bf16)a.w;
    o[4] = (bf16)c.x; o[5] = (bf16)c.y; o[6] = (bf16)c.z; o[7] = (bf16)c.w;
    *(bf16x8*)(p.xbf + i) = o;
  } else {  // ---- G build: G[j,d] = sum_{k: perm[k]==d} W_dec[j,k] ----
    const int j = b - 8192;
    float* row = (float*)smem;               // 1024 floats (4096 B)
    int* perm_l = (int*)(smem + 4096);       // 256 ints
    int* nzp = (int*)(smem + 4096 + 1024);   // 1 int
#pragma unroll
    for (int c = 0; c < 4; c++) row[tid * 4 + c] = 0.f;
    if (tid == 0) *nzp = 0;
    __syncthreads();
    // detect int64 vs int32 device layout: int64 little-endian has all-zero
    // high words; int32 random perm has ~0 chance of 128 zero odd entries.
    if (tid < 128 && p.praw[2 * tid + 1] != 0) atomicOr(nzp, 1);
    __syncthreads();
    const int is64 = (*nzp == 0);
    perm_l[tid] = is64 ? p.praw[2 * tid] : p.praw[tid];
    __syncthreads();
    atomicAdd(&row[perm_l[tid]], p.Wdec[(size_t)j * 256 + tid]);
    __syncthreads();
#pragma unroll
    for (int c = 0; c < 4; c++)
      p.Gbf[(size_t)j * 1024 + tid * 4 + c] = (bf16)row[tid * 4 + c];
  }
}

// ---------------------------------------------------------------------------
// 64x64-tile NT GEMM, all matrices 1024x1024 bf16, C = A * B^T (bf16 out).
// 256 thr = 4 waves in 2x2; each wave 32x32 (2x2 MFMA 16x16x32 frags).
// Batched via blockIdx.z with pointer tables.
// ---------------------------------------------------------------------------
struct GemmBatch { const bf16* A[6]; const bf16* B[6]; bf16* C[6]; };

__global__ __launch_bounds__(256) void gemm64_nt(GemmBatch bt) {
  const bf16* __restrict__ A = bt.A[blockIdx.z];
  const bf16* __restrict__ B = bt.B[blockIdx.z];
  bf16* __restrict__ C = bt.C[blockIdx.z];

  __shared__ bf16 As[64 * 32];
  __shared__ bf16 Bs[64 * 32];

  const int tid = threadIdx.x;
  const int wave = tid >> 6, lane = tid & 63;
  const int quad = lane >> 4, l16 = lane & 15;
  const int rowBase = blockIdx.y * 64;
  const int colBase = blockIdx.x * 64;
  const int waveM = (wave >> 1) * 32, waveN = (wave & 1) * 32;

  const int e = tid * 8;
  const int sr = e >> 5, sc = e & 31;
  const bf16* Ag = A + (size_t)(rowBase + sr) * 1024 + sc;
  const bf16* Bg = B + (size_t)(colBase + sr) * 1024 + sc;
  char* AsB = (char*)As + wave * 1024;
  char* BsB = (char*)Bs + wave * 1024;

  f32x4 acc[2][2] = {};

  for (int k0 = 0; k0 < 1024; k0 += 32) {
    global_to_lds16(Ag + k0, AsB);
    global_to_lds16(Bg + k0, BsB);
    __syncthreads();
    bf16x8 af[2], bfr[2];
#pragma unroll
    for (int mi = 0; mi < 2; mi++)
      af[mi] = *(const bf16x8*)(As + (waveM + mi * 16 + l16) * 32 + quad * 8);
#pragma unroll
    for (int ni = 0; ni < 2; ni++)
      bfr[ni] = *(const bf16x8*)(Bs + (waveN + ni * 16 + l16) * 32 + quad * 8);
#pragma unroll
    for (int mi = 0; mi < 2; mi++)
#pragma unroll
      for (int ni = 0; ni < 2; ni++)
        acc[mi][ni] = __builtin_amdgcn_mfma_f32_16x16x32_bf16(af[mi], bfr[ni],
                                                              acc[mi][ni], 0, 0, 0);
    __syncthreads();
  }

  bf16* Cb = C + (size_t)(rowBase + waveM) * 1024 + colBase + waveN;
#pragma unroll
  for (int mi = 0; mi < 2; mi++)
#pragma unroll
    for (int ni = 0; ni < 2; ni++)
#pragma unroll
      for (int r = 0; r < 4; r++)
        Cb[(size_t)(mi * 16 + quad * 4 + r) * 1024 + ni * 16 + l16] =
            (bf16)acc[mi][ni][r];
}

// ---------------------------------------------------------------------------
// 128x128-tile NT GEMM (m97 structure): out = x * F^T, fp32 out.
// M=8192, N=1024, K=1024, lda=ldb=ldc=1024.
// ---------------------------------------------------------------------------
__global__ __launch_bounds__(256) void gemm128_nt_f32(const bf16* __restrict__ A,
                                                      const bf16* __restrict__ B,
                                                      float* __restrict__ C) {
  __shared__ bf16 As[128 * 32];
  __shared__ bf16 Bs[128 * 32];

  const int tid = threadIdx.x;
  const int wave = tid >> 6, lane = tid & 63;
  const int quad = lane >> 4, l16 = lane & 15;
  const int rowBase = blockIdx.y * 128;
  const int colBase = blockIdx.x * 128;
  const int waveM = (wave >> 1) * 64, waveN = (wave & 1) * 64;

  const int e = tid * 8;
  const int sr = e >> 5, sc = e & 31;
  const bf16* Ag0 = A + (size_t)(rowBase + sr) * 1024 + sc;
  const bf16* Ag1 = Ag0 + (size_t)64 * 1024;
  const bf16* Bg0 = B + (size_t)(colBase + sr) * 1024 + sc;
  const bf16* Bg1 = Bg0 + (size_t)64 * 1024;
  char* AsB0 = (char*)As + wave * 1024;
  char* AsB1 = AsB0 + 4096;
  char* BsB0 = (char*)Bs + wave * 1024;
  char* BsB1 = BsB0 + 4096;

  f32x4 acc[4][4] = {};

  for (int k0 = 0; k0 < 1024; k0 += 32) {
    global_to_lds16(Ag0 + k0, AsB0);
    global_to_lds16(Ag1 + k0, AsB1);
    global_to_lds16(Bg0 + k0, BsB0);
    global_to_lds16(Bg1 + k0, BsB1);
    __syncthreads();
    bf16x8 af[4], bfr[4];
#pragma unroll
    for (int mi = 0; mi < 4; mi++)
      af[mi] = *(const bf16x8*)(As + (waveM + mi * 16 + l16) * 32 + quad * 8);
#pragma unroll
    for (int ni = 0; ni < 4; ni++)
      bfr[ni] = *(const bf16x8*)(Bs + (waveN + ni * 16 + l16) * 32 + quad * 8);
#pragma unroll
    for (int mi = 0; mi < 4; mi++)
#pragma unroll
      for (int ni = 0; ni < 4; ni++)
        acc[mi][ni] = __builtin_amdgcn_mfma_f32_16x16x32_bf16(af[mi], bfr[ni],
                                                              acc[mi][ni], 0, 0, 0);
    __syncthreads();
  }

  float* Cb = C + (size_t)(rowBase + waveM) * 1024 + colBase + waveN;
#pragma unroll
  for (int mi = 0; mi < 4; mi++)
#pragma unroll
    for (int ni = 0; ni < 4; ni++)
#pragma unroll
      for (int r = 0; r < 4; r++)
        Cb[(size_t)(mi * 16 + quad * 4 + r) * 1024 + ni * 16 + l16] =
            acc[mi][ni][r];
}

// ---------------------------------------------------------------------------
// Host launcher.  6 kernels total (was 12).
// out = x @ (G * W9 * W8 * W8 * W7 * W6 * W5 * W4 * W3 * W2 * W1 * W0)^T
// Tree: P0=G*W9  P1=(W8*W8)^T  P2=W7*W6  P3=(W5*W4)^T  P4=W3*W2  P5=(W1*W0)^T
//       Q0=NT(P0,P1) Q1t=NT(P3,P2) Q2t=NT(P5,P4); R=NT(Q0,Q1t); F=NT(R,Q2t)
//       out = NT(x, F).   NT(A,B) = A*B^T; transposed nodes via (AB)^T=NT(B^T,A).
// ---------------------------------------------------------------------------
extern "C" void kernel_launch(void* const* d_in, const int* in_sizes, int n_in,
                              void* d_out, int out_size, void* d_ws, size_t ws_size,
                              hipStream_t stream) {
  const float* x    = (const float*)d_in[0];
  const float* Wsrc = (const float*)d_in[1];   // 10 x 1024 x 1024
  const float* Wdec = (const float*)d_in[2];   // 1024 x 256
  const int*   praw = (const int*)d_in[3];
  float* out = (float*)d_out;

  constexpr size_t MAT  = 1024ull * 1024ull;
  constexpr size_t SLOT = 2ull * 1024 * 1024;  // 2 MiB = one bf16 DxD matrix

  char* ws = (char*)d_ws;
  bf16* Wrm[5];  // W1, W3, W5, W7, W8 (row-major bf16)
  for (int i = 0; i < 5; i++) Wrm[i] = (bf16*)(ws + (size_t)i * SLOT);
  bf16* Wt[6];   // W0^T, W2^T, W4^T, W6^T, W8^T, W9^T
  for (int i = 0; i < 6; i++) Wt[i] = (bf16*)(ws + (size_t)(5 + i) * SLOT);
  bf16* Gbf = (bf16*)(ws + 11 * SLOT);
  bf16* xbf = (bf16*)(ws + 12 * SLOT);         // 8 slots (16 MiB)
  bf16* P[6];
  for (int i = 0; i < 6; i++) P[i] = (bf16*)(ws + (size_t)(20 + i) * SLOT);
  bf16* Q[3];
  for (int i = 0; i < 3; i++) Q[i] = (bf16*)(ws + (size_t)(26 + i) * SLOT);
  bf16* Rb = (bf16*)(ws + 29 * SLOT);
  bf16* Fb = (bf16*)(ws + 30 * SLOT);          // total ws use: 62 MiB

  // 1) ONE fused prep kernel (converts, transposes, x, G) — 9216 indep blocks
  PrepArgs pa;
  const int rmIdx[5] = {1, 3, 5, 7, 8};
  for (int i = 0; i < 5; i++) { pa.cvt_src[i] = Wsrc + (size_t)rmIdx[i] * MAT; pa.cvt_dst[i] = Wrm[i]; }
  const int trIdx[6] = {0, 2, 4, 6, 8, 9};
  for (int i = 0; i < 6; i++) { pa.tr_src[i] = Wsrc + (size_t)trIdx[i] * MAT; pa.tr_dst[i] = Wt[i]; }
  pa.x = x; pa.xbf = xbf; pa.Wdec = Wdec; pa.praw = praw; pa.Gbf = Gbf;
  prep_all<<<dim3(9216), 256, 0, stream>>>(pa);

  // 2) tree level 1 (6 GEMMs, batched)
  GemmBatch L1;
  const bf16* l1a[6] = {Gbf, Wt[4], Wrm[3], Wt[2], Wrm[1], Wt[0]};
  const bf16* l1b[6] = {Wt[5], Wrm[4], Wt[3], Wrm[2], Wt[1], Wrm[0]};
  for (int i = 0; i < 6; i++) { L1.A[i] = l1a[i]; L1.B[i] = l1b[i]; L1.C[i] = P[i]; }
  gemm64_nt<<<dim3(16, 16, 6), 256, 0, stream>>>(L1);

  // 3) tree level 2 (3 GEMMs): Q0=NT(P0,P1t) Q1t=NT(P3t,P2) Q2t=NT(P5t,P4)
  GemmBatch L2;
  const bf16* l2a[3] = {P[0], P[3], P[5]};
  const bf16* l2b[3] = {P[1], P[2], P[4]};
  for (int i = 0; i < 3; i++) { L2.A[i] = l2a[i]; L2.B[i] = l2b[i]; L2.C[i] = Q[i]; }
  gemm64_nt<<<dim3(16, 16, 3), 256, 0, stream>>>(L2);

  // 4) level 3: R = NT(Q0, Q1t)
  GemmBatch L3{};
  L3.A[0] = Q[0]; L3.B[0] = Q[1]; L3.C[0] = Rb;
  gemm64_nt<<<dim3(16, 16, 1), 256, 0, stream>>>(L3);

  // 5) level 4: F = NT(R, Q2t)
  GemmBatch L4{};
  L4.A[0] = Rb; L4.B[0] = Q[2]; L4.C[0] = Fb;
  gemm64_nt<<<dim3(16, 16, 1), 256, 0, stream>>>(L4);

  // 6) out = NT(x, F), fp32 out
  gemm128_nt_f32<<<dim3(8, 64), 256, 0, stream>>>(xbf, Fb, out);

  (void)in_sizes; (void)n_in; (void)out_size; (void)ws_size;
}